// Round 1
// baseline (1019.980 us; speedup 1.0000x reference)
//
#include <hip/hip_runtime.h>
#include <stdint.h>

typedef _Float16 f16;
typedef _Float16 f16x8 __attribute__((ext_vector_type(8)));
typedef _Float16 f16x4 __attribute__((ext_vector_type(4)));
typedef float    f32x4 __attribute__((ext_vector_type(4)));

#define SEQ   2048
#define EDIM  2048
#define NHQ   32
#define NHKV  8
#define DHEAD 64
#define KVD   512
#define NB    2
#define NTOK  (NB*SEQ)
#define SCALE 0.1803368801111204f   // log2(e)/8

__device__ __forceinline__ f32x4 mfma16(f16x8 a, f16x8 b, f32x4 c) {
  return __builtin_amdgcn_mfma_f32_16x16x32_f16(a, b, c, 0, 0, 0);
}

__device__ __forceinline__ void gload_lds16(const void* g, void* l) {
  __builtin_amdgcn_global_load_lds(
      (const __attribute__((address_space(1))) void*)g,
      (__attribute__((address_space(3))) void*)l, 16, 0, 0);
}

// ---------------- convert f32 -> f16 (vectorized) ----------------
__global__ __launch_bounds__(256) void k_cvt(const float* __restrict__ s,
                                             f16* __restrict__ d, int n4) {
  int i = blockIdx.x * 256 + threadIdx.x;
  if (i >= n4) return;
  float4 v = reinterpret_cast<const float4*>(s)[i];
  f16x4 h;
  h[0] = (f16)v.x; h[1] = (f16)v.y; h[2] = (f16)v.z; h[3] = (f16)v.w;
  reinterpret_cast<f16x4*>(d)[i] = h;
}

// ---------------- transpose+convert: f32 [R][C] -> f16 [C][R] ----------------
__global__ __launch_bounds__(256) void k_tconv(const float* __restrict__ s,
                                               f16* __restrict__ d, int R, int C) {
  __shared__ float t[32][33];
  int tr = blockIdx.x, tc = blockIdx.y;
  int lr = threadIdx.x >> 3;
  int lc = (threadIdx.x & 7) << 2;
  float4 v = *reinterpret_cast<const float4*>(&s[(size_t)(tr*32+lr)*C + tc*32 + lc]);
  t[lr][lc+0] = v.x; t[lr][lc+1] = v.y; t[lr][lc+2] = v.z; t[lr][lc+3] = v.w;
  __syncthreads();
  f16x4 h;
  h[0] = (f16)t[lc+0][lr];
  h[1] = (f16)t[lc+1][lr];
  h[2] = (f16)t[lc+2][lr];
  h[3] = (f16)t[lc+3][lr];
  *reinterpret_cast<f16x4*>(&d[(size_t)(tc*32+lr)*R + tr*32 + lc]) = h;
}

// ---------------- transpose V: [4096][512] f16 -> Vt [16][64][2048] f16 ----------------
__global__ __launch_bounds__(256) void k_trv(const f16* __restrict__ src,
                                             f16* __restrict__ dst) {
  __shared__ f16 t[64][68];
  int bh = blockIdx.x;            // b*8 + hkv
  int st = blockIdx.y;            // s tile (64)
  int b = bh >> 3, h = bh & 7;
  #pragma unroll
  for (int i = 0; i < 4; ++i) {
    int sl = i*16 + (threadIdx.x >> 4);
    int d4 = (threadIdx.x & 15) * 4;
    *(f16x4*)&t[sl][d4] =
        *(const f16x4*)&src[(size_t)(b*SEQ + st*64 + sl)*KVD + h*DHEAD + d4];
  }
  __syncthreads();
  #pragma unroll
  for (int i = 0; i < 4; ++i) {
    int dl = i*16 + (threadIdx.x >> 4);
    int s4 = (threadIdx.x & 15) * 4;
    f16x4 v;
    v[0] = t[s4+0][dl]; v[1] = t[s4+1][dl]; v[2] = t[s4+2][dl]; v[3] = t[s4+3][dl];
    *(f16x4*)&dst[(size_t)(bh*DHEAD + dl)*SEQ + st*64 + s4] = v;
  }
}

// ---------------- GEMM: C[M,N] = A[M,K] * Bt[N,K]^T + bias ----------------
// 128x128 tile, BK=64, 4 waves (2x2), global_load_lds staging, XOR-swizzled LDS.
template<int F16OUT>
__global__ __launch_bounds__(256) void k_gemm(
    const f16* __restrict__ A, const f16* __restrict__ Bt,
    const float* __restrict__ bias, void* __restrict__ Cout,
    int M, int N, int K)
{
  __shared__ f16 sA[128*64];
  __shared__ f16 sB[128*64];
  const int tid  = threadIdx.x;
  const int lane = tid & 63, wv = tid >> 6;
  const int tn = blockIdx.x, tm = blockIdx.y;
  const int wm = wv >> 1, wn = wv & 1;
  const int l15 = lane & 15, lhi = lane >> 4;

  const f32x4 zz = {0.f, 0.f, 0.f, 0.f};
  f32x4 acc[4][4];
  #pragma unroll
  for (int m = 0; m < 4; ++m)
    #pragma unroll
    for (int n = 0; n < 4; ++n) acc[m][n] = zz;

  // staging: 8 units per wave (1 KB each); units 0..15 = A, 16..31 = B
  const f16* gsrc[8];
  f16* ldst[8];
  #pragma unroll
  for (int i = 0; i < 8; ++i) {
    int u = wv*8 + i;
    int r  = (u & 15)*8 + (lane >> 3);
    int cb = ((lane & 7) << 4) ^ ((r & 7) << 4);   // swizzled source col (bytes)
    if (u < 16) {
      gsrc[i] = A  + (size_t)(tm*128 + r)*K + (cb >> 1);
      ldst[i] = sA + u*512;
    } else {
      gsrc[i] = Bt + (size_t)(tn*128 + r)*K + (cb >> 1);
      ldst[i] = sB + (u - 16)*512;
    }
  }

  // fragment LDS byte offsets (k-iteration independent)
  int aoff[2][4], boff[2][4];
  #pragma unroll
  for (int ks = 0; ks < 2; ++ks)
    #pragma unroll
    for (int m = 0; m < 4; ++m) {
      int ra = wm*64 + m*16 + l15;
      aoff[ks][m] = ra*128 + ((ks*64 + (lhi << 4)) ^ ((ra & 7) << 4));
      int rb = wn*64 + m*16 + l15;
      boff[ks][m] = rb*128 + ((ks*64 + (lhi << 4)) ^ ((rb & 7) << 4));
    }

  const int nkb = K >> 6;
  for (int kb = 0; kb < nkb; ++kb) {
    #pragma unroll
    for (int i = 0; i < 8; ++i)
      gload_lds16(gsrc[i] + kb*64, ldst[i]);
    __syncthreads();
    #pragma unroll
    for (int ks = 0; ks < 2; ++ks) {
      f16x8 af[4], bf[4];
      #pragma unroll
      for (int m = 0; m < 4; ++m)
        af[m] = *(const f16x8*)((const char*)sA + aoff[ks][m]);
      #pragma unroll
      for (int n = 0; n < 4; ++n)
        bf[n] = *(const f16x8*)((const char*)sB + boff[ks][n]);
      #pragma unroll
      for (int m = 0; m < 4; ++m)
        #pragma unroll
        for (int n = 0; n < 4; ++n)
          acc[m][n] = mfma16(af[m], bf[n], acc[m][n]);
    }
    __syncthreads();
  }

  // epilogue
  float bcol[4];
  #pragma unroll
  for (int n = 0; n < 4; ++n)
    bcol[n] = bias[tn*128 + wn*64 + n*16 + l15];
  #pragma unroll
  for (int m = 0; m < 4; ++m)
    #pragma unroll
    for (int n = 0; n < 4; ++n)
      #pragma unroll
      for (int r = 0; r < 4; ++r) {
        int row = tm*128 + wm*64 + m*16 + lhi*4 + r;
        int col = tn*128 + wn*64 + n*16 + l15;
        float v = acc[m][n][r] + bcol[n];
        if (F16OUT) ((f16*)Cout)[(size_t)row*N + col] = (f16)v;
        else        ((float*)Cout)[(size_t)row*N + col] = v;
      }
}

// ---------------- fused GQA attention ----------------
// grid: 1024 blocks (b*512 + h*16 + qb), 4 waves, each wave owns 32 q-rows.
// Pass A: denominator sums (no max needed: scores bounded, exp2 safe in f32).
// Pass B: recompute scores, write normalized weights (f32, 1.07 GB), PV via MFMA.
__global__ __launch_bounds__(256) void k_attn(
    const f16* __restrict__ Qp,   // [4096][2048]
    const f16* __restrict__ Kp,   // [4096][512]
    const f16* __restrict__ Vt,   // [16][64][2048]
    float* __restrict__ wout,     // [2][32][2048][2048]
    f16* __restrict__ AO)         // [4096][2048]
{
  __shared__ f16 sw[4][32*128];   // per-wave swizzled w tile (8 KB each)
  const int tid = threadIdx.x, lane = tid & 63, wv = tid >> 6;
  const int bid = blockIdx.x;
  const int b = bid >> 9, h = (bid >> 4) & 31, qb = bid & 15;
  const int hk = h >> 2;
  const int l15 = lane & 15, lhi = lane >> 4;
  const int qrow0 = qb*128 + wv*32;
  const f32x4 zz = {0.f, 0.f, 0.f, 0.f};

  // Q fragments (reused for whole kernel)
  f16x8 qf[2][2];
  #pragma unroll
  for (int qt = 0; qt < 2; ++qt)
    #pragma unroll
    for (int ks = 0; ks < 2; ++ks)
      qf[qt][ks] = *(const f16x8*)&Qp[(size_t)(b*SEQ + qrow0 + qt*16 + l15)*EDIM
                                      + h*DHEAD + ks*32 + lhi*8];

  const f16* Kb = Kp + (size_t)(b*SEQ)*KVD + hk*DHEAD;

  // ---- pass A: per-lane partial denominators ----
  float lsum[2][4];
  #pragma unroll
  for (int qt = 0; qt < 2; ++qt)
    #pragma unroll
    for (int r = 0; r < 4; ++r) lsum[qt][r] = 0.f;

  for (int k0 = 0; k0 < SEQ; k0 += 16) {
    f16x8 kf0 = *(const f16x8*)&Kb[(size_t)(k0 + l15)*KVD + lhi*8];
    f16x8 kf1 = *(const f16x8*)&Kb[(size_t)(k0 + l15)*KVD + 32 + lhi*8];
    #pragma unroll
    for (int qt = 0; qt < 2; ++qt) {
      f32x4 s = zz;
      s = mfma16(qf[qt][0], kf0, s);
      s = mfma16(qf[qt][1], kf1, s);
      #pragma unroll
      for (int r = 0; r < 4; ++r)
        lsum[qt][r] += __builtin_amdgcn_exp2f(s[r] * SCALE);
    }
  }
  // reduce across the 16 lanes holding one row's columns
  float rinv[2][4];
  #pragma unroll
  for (int qt = 0; qt < 2; ++qt)
    #pragma unroll
    for (int r = 0; r < 4; ++r) {
      float v = lsum[qt][r];
      v += __shfl_xor(v, 1); v += __shfl_xor(v, 2);
      v += __shfl_xor(v, 4); v += __shfl_xor(v, 8);
      rinv[qt][r] = __builtin_amdgcn_rcpf(v);
    }

  // ---- pass B: weights out + PV ----
  f32x4 o[2][4];
  #pragma unroll
  for (int qt = 0; qt < 2; ++qt)
    #pragma unroll
    for (int dt = 0; dt < 4; ++dt) o[qt][dt] = zz;

  char* swv = (char*)&sw[wv][0];
  float* wrow = wout + ((size_t)((b*NHQ + h)*SEQ + qrow0))*SEQ;
  const f16* Vb = Vt + (size_t)((b*NHKV + hk)*DHEAD)*SEQ;

  for (int kb = 0; kb < SEQ; kb += 128) {
    #pragma unroll
    for (int kt = 0; kt < 8; ++kt) {
      int k0 = kb + kt*16;
      f16x8 kf0 = *(const f16x8*)&Kb[(size_t)(k0 + l15)*KVD + lhi*8];
      f16x8 kf1 = *(const f16x8*)&Kb[(size_t)(k0 + l15)*KVD + 32 + lhi*8];
      #pragma unroll
      for (int qt = 0; qt < 2; ++qt) {
        f32x4 s = zz;
        s = mfma16(qf[qt][0], kf0, s);
        s = mfma16(qf[qt][1], kf1, s);
        #pragma unroll
        for (int r = 0; r < 4; ++r) {
          float w = __builtin_amdgcn_exp2f(s[r] * SCALE) * rinv[qt][r];
          int qloc = qt*16 + lhi*4 + r;
          wrow[(size_t)qloc*SEQ + k0 + l15] = w;
          int cbyte = (kt*32 + l15*2) ^ ((qloc & 15) << 4);
          *(f16*)(swv + qloc*256 + cbyte) = (f16)w;
        }
      }
    }
    // PV: o += w_tile[32 x 128] * V[128 x 64]
    #pragma unroll
    for (int ks = 0; ks < 4; ++ks) {
      f16x8 af[2];
      #pragma unroll
      for (int qt = 0; qt < 2; ++qt) {
        int row = qt*16 + l15;
        int cb = (ks*64 + lhi*16) ^ ((row & 15) << 4);
        af[qt] = *(const f16x8*)(swv + row*256 + cb);
      }
      #pragma unroll
      for (int dt = 0; dt < 4; ++dt) {
        f16x8 vf = *(const f16x8*)&Vb[(size_t)(dt*16 + l15)*SEQ + kb + ks*32 + lhi*8];
        o[0][dt] = mfma16(af[0], vf, o[0][dt]);
        o[1][dt] = mfma16(af[1], vf, o[1][dt]);
      }
    }
  }

  // write attn_out (f16) in [B,S,HQ*DH] layout for the output GEMM
  #pragma unroll
  for (int qt = 0; qt < 2; ++qt)
    #pragma unroll
    for (int dt = 0; dt < 4; ++dt)
      #pragma unroll
      for (int r = 0; r < 4; ++r) {
        int q = qrow0 + qt*16 + lhi*4 + r;
        AO[(size_t)(b*SEQ + q)*EDIM + h*DHEAD + dt*16 + l15] = (f16)o[qt][dt][r];
      }
}

// ---------------- launch ----------------
extern "C" void kernel_launch(void* const* d_in, const int* in_sizes, int n_in,
                              void* d_out, int out_size, void* d_ws, size_t ws_size,
                              hipStream_t stream) {
  (void)in_sizes; (void)n_in; (void)out_size; (void)ws_size;
  const float* query = (const float*)d_in[0];
  const float* key   = (const float*)d_in[1];
  const float* value = (const float*)d_in[2];
  const float* Wq    = (const float*)d_in[3];
  const float* bq    = (const float*)d_in[4];
  const float* Wk    = (const float*)d_in[5];
  const float* bk    = (const float*)d_in[6];
  const float* Wv    = (const float*)d_in[7];
  const float* bv    = (const float*)d_in[8];
  const float* Wo    = (const float*)d_in[9];
  const float* bo    = (const float*)d_in[10];

  float* out   = (float*)d_out;
  float* wattn = out + (size_t)NTOK*EDIM;

  f16* p   = (f16*)d_ws;
  f16* q16 = p;  p += (size_t)NTOK*EDIM;
  f16* k16 = p;  p += (size_t)NTOK*EDIM;
  f16* v16 = p;  p += (size_t)NTOK*EDIM;
  f16* wqT = p;  p += (size_t)EDIM*EDIM;
  f16* wkT = p;  p += (size_t)KVD*EDIM;
  f16* wvT = p;  p += (size_t)KVD*EDIM;
  f16* woT = p;  p += (size_t)EDIM*EDIM;
  f16* Qp  = p;  p += (size_t)NTOK*EDIM;
  f16* Kp  = p;  p += (size_t)NTOK*KVD;
  f16* Vp  = p;  p += (size_t)NTOK*KVD;
  f16* Vt  = p;  p += (size_t)NTOK*KVD;
  f16* AO  = p;  p += (size_t)NTOK*EDIM;

  const int n4 = NTOK*EDIM/4;                       // 2097152
  k_cvt<<<n4/256, 256, 0, stream>>>(query, q16, n4);
  k_cvt<<<n4/256, 256, 0, stream>>>(key,   k16, n4);
  k_cvt<<<n4/256, 256, 0, stream>>>(value, v16, n4);

  k_tconv<<<dim3(EDIM/32, EDIM/32), 256, 0, stream>>>(Wq, wqT, EDIM, EDIM);
  k_tconv<<<dim3(EDIM/32, KVD/32),  256, 0, stream>>>(Wk, wkT, EDIM, KVD);
  k_tconv<<<dim3(EDIM/32, KVD/32),  256, 0, stream>>>(Wv, wvT, EDIM, KVD);
  k_tconv<<<dim3(EDIM/32, EDIM/32), 256, 0, stream>>>(Wo, woT, EDIM, EDIM);

  k_gemm<1><<<dim3(EDIM/128, NTOK/128), 256, 0, stream>>>(q16, wqT, bq, Qp, NTOK, EDIM, EDIM);
  k_gemm<1><<<dim3(KVD/128,  NTOK/128), 256, 0, stream>>>(k16, wkT, bk, Kp, NTOK, KVD,  EDIM);
  k_gemm<1><<<dim3(KVD/128,  NTOK/128), 256, 0, stream>>>(v16, wvT, bv, Vp, NTOK, KVD,  EDIM);

  k_trv<<<dim3(NB*NHKV, SEQ/64), 256, 0, stream>>>(Vp, Vt);

  k_attn<<<NB*NHQ*(SEQ/128), 256, 0, stream>>>(Qp, Kp, Vt, wattn, AO);

  k_gemm<0><<<dim3(EDIM/128, NTOK/128), 256, 0, stream>>>(AO, woT, bo, out, NTOK, EDIM, EDIM);
}

// Round 2
// 602.374 us; speedup vs baseline: 1.6933x; 1.6933x over previous
//
#include <hip/hip_runtime.h>
#include <stdint.h>

typedef _Float16 f16;
typedef _Float16 f16x8 __attribute__((ext_vector_type(8)));
typedef _Float16 f16x4 __attribute__((ext_vector_type(4)));
typedef float    f32x4 __attribute__((ext_vector_type(4)));

#define SEQ   2048
#define EDIM  2048
#define NHQ   32
#define NHKV  8
#define DHEAD 64
#define KVD   512
#define NB    2
#define NTOK  (NB*SEQ)
#define SCALE 0.1803368801111204f   // log2(e)/8

__device__ __forceinline__ f32x4 mfma16(f16x8 a, f16x8 b, f32x4 c) {
  return __builtin_amdgcn_mfma_f32_16x16x32_f16(a, b, c, 0, 0, 0);
}

__device__ __forceinline__ void gload_lds16(const void* g, void* l) {
  __builtin_amdgcn_global_load_lds(
      (const __attribute__((address_space(1))) void*)g,
      (__attribute__((address_space(3))) void*)l, 16, 0, 0);
}

// ---------------- convert f32 -> f16 (vectorized) ----------------
__global__ __launch_bounds__(256) void k_cvt(const float* __restrict__ s,
                                             f16* __restrict__ d, int n4) {
  int i = blockIdx.x * 256 + threadIdx.x;
  if (i >= n4) return;
  float4 v = reinterpret_cast<const float4*>(s)[i];
  f16x4 h;
  h[0] = (f16)v.x; h[1] = (f16)v.y; h[2] = (f16)v.z; h[3] = (f16)v.w;
  reinterpret_cast<f16x4*>(d)[i] = h;
}

// ---------------- transpose+convert: f32 [R][C] -> f16 [C][R] ----------------
__global__ __launch_bounds__(256) void k_tconv(const float* __restrict__ s,
                                               f16* __restrict__ d, int R, int C) {
  __shared__ float t[32][33];
  int tr = blockIdx.x, tc = blockIdx.y;
  int lr = threadIdx.x >> 3;
  int lc = (threadIdx.x & 7) << 2;
  float4 v = *reinterpret_cast<const float4*>(&s[(size_t)(tr*32+lr)*C + tc*32 + lc]);
  t[lr][lc+0] = v.x; t[lr][lc+1] = v.y; t[lr][lc+2] = v.z; t[lr][lc+3] = v.w;
  __syncthreads();
  f16x4 h;
  h[0] = (f16)t[lc+0][lr];
  h[1] = (f16)t[lc+1][lr];
  h[2] = (f16)t[lc+2][lr];
  h[3] = (f16)t[lc+3][lr];
  *reinterpret_cast<f16x4*>(&d[(size_t)(tc*32+lr)*R + tr*32 + lc]) = h;
}

// ---------------- transpose V: [4096][512] f16 -> Vt [16][64][2048] f16 ----------------
__global__ __launch_bounds__(256) void k_trv(const f16* __restrict__ src,
                                             f16* __restrict__ dst) {
  __shared__ f16 t[64][68];
  int bh = blockIdx.x;            // b*8 + hkv
  int st = blockIdx.y;            // s tile (64)
  int b = bh >> 3, h = bh & 7;
  #pragma unroll
  for (int i = 0; i < 4; ++i) {
    int sl = i*16 + (threadIdx.x >> 4);
    int d4 = (threadIdx.x & 15) * 4;
    *(f16x4*)&t[sl][d4] =
        *(const f16x4*)&src[(size_t)(b*SEQ + st*64 + sl)*KVD + h*DHEAD + d4];
  }
  __syncthreads();
  #pragma unroll
  for (int i = 0; i < 4; ++i) {
    int dl = i*16 + (threadIdx.x >> 4);
    int s4 = (threadIdx.x & 15) * 4;
    f16x4 v;
    v[0] = t[s4+0][dl]; v[1] = t[s4+1][dl]; v[2] = t[s4+2][dl]; v[3] = t[s4+3][dl];
    *(f16x4*)&dst[(size_t)(bh*DHEAD + dl)*SEQ + st*64 + s4] = v;
  }
}

// ---------------- GEMM: C[M,N] = A[M,K] * Bt[N,K]^T + bias ----------------
template<int F16OUT>
__global__ __launch_bounds__(256) void k_gemm(
    const f16* __restrict__ A, const f16* __restrict__ Bt,
    const float* __restrict__ bias, void* __restrict__ Cout,
    int M, int N, int K)
{
  __shared__ f16 sA[128*64];
  __shared__ f16 sB[128*64];
  const int tid  = threadIdx.x;
  const int lane = tid & 63, wv = tid >> 6;
  const int tn = blockIdx.x, tm = blockIdx.y;
  const int wm = wv >> 1, wn = wv & 1;
  const int l15 = lane & 15, lhi = lane >> 4;

  const f32x4 zz = {0.f, 0.f, 0.f, 0.f};
  f32x4 acc[4][4];
  #pragma unroll
  for (int m = 0; m < 4; ++m)
    #pragma unroll
    for (int n = 0; n < 4; ++n) acc[m][n] = zz;

  const f16* gsrc[8];
  f16* ldst[8];
  #pragma unroll
  for (int i = 0; i < 8; ++i) {
    int u = wv*8 + i;
    int r  = (u & 15)*8 + (lane >> 3);
    int cb = ((lane & 7) << 4) ^ ((r & 7) << 4);
    if (u < 16) {
      gsrc[i] = A  + (size_t)(tm*128 + r)*K + (cb >> 1);
      ldst[i] = sA + u*512;
    } else {
      gsrc[i] = Bt + (size_t)(tn*128 + r)*K + (cb >> 1);
      ldst[i] = sB + (u - 16)*512;
    }
  }

  int aoff[2][4], boff[2][4];
  #pragma unroll
  for (int ks = 0; ks < 2; ++ks)
    #pragma unroll
    for (int m = 0; m < 4; ++m) {
      int ra = wm*64 + m*16 + l15;
      aoff[ks][m] = ra*128 + ((ks*64 + (lhi << 4)) ^ ((ra & 7) << 4));
      int rb = wn*64 + m*16 + l15;
      boff[ks][m] = rb*128 + ((ks*64 + (lhi << 4)) ^ ((rb & 7) << 4));
    }

  const int nkb = K >> 6;
  for (int kb = 0; kb < nkb; ++kb) {
    #pragma unroll
    for (int i = 0; i < 8; ++i)
      gload_lds16(gsrc[i] + kb*64, ldst[i]);
    __syncthreads();
    #pragma unroll
    for (int ks = 0; ks < 2; ++ks) {
      f16x8 af[4], bf[4];
      #pragma unroll
      for (int m = 0; m < 4; ++m)
        af[m] = *(const f16x8*)((const char*)sA + aoff[ks][m]);
      #pragma unroll
      for (int n = 0; n < 4; ++n)
        bf[n] = *(const f16x8*)((const char*)sB + boff[ks][n]);
      #pragma unroll
      for (int m = 0; m < 4; ++m)
        #pragma unroll
        for (int n = 0; n < 4; ++n)
          acc[m][n] = mfma16(af[m], bf[n], acc[m][n]);
    }
    __syncthreads();
  }

  float bcol[4];
  #pragma unroll
  for (int n = 0; n < 4; ++n)
    bcol[n] = bias[tn*128 + wn*64 + n*16 + l15];
  #pragma unroll
  for (int m = 0; m < 4; ++m)
    #pragma unroll
    for (int n = 0; n < 4; ++n)
      #pragma unroll
      for (int r = 0; r < 4; ++r) {
        int row = tm*128 + wm*64 + m*16 + lhi*4 + r;
        int col = tn*128 + wn*64 + n*16 + l15;
        float v = acc[m][n][r] + bcol[n];
        if (F16OUT) ((f16*)Cout)[(size_t)row*N + col] = (f16)v;
        else        ((float*)Cout)[(size_t)row*N + col] = v;
      }
}

// ---------------- fused GQA attention ----------------
// grid 2048: bid = b*1024 + h*32 + qb. Block = 64 q rows, 4 waves x 16 rows.
// K/V staged in LDS per 64-k block (global_load_lds, XOR-swizzled via source).
// Swapped-operand QK^T: lane holds 4 consecutive k for one q row ->
// float4 nontemporal weight stores, scalar per-lane denominator.
__global__ __launch_bounds__(256) void k_attn(
    const f16* __restrict__ Qp,   // [4096][2048]
    const f16* __restrict__ Kp,   // [4096][512]
    const f16* __restrict__ Vt,   // [16][64][2048]
    float* __restrict__ wout,     // [2][32][2048][2048]
    f16* __restrict__ AO)         // [4096][2048]
{
  __shared__ f16 sK[64*64];       // 8 KB, K tile [64 k][64 d], source-swizzled
  __shared__ f16 sV[64*64];       // 8 KB, V^T tile [64 d][64 k], source-swizzled
  __shared__ f16 sW[4*16*64];     // 8 KB, per-wave w tile [16 q][64 k]
  const int tid = threadIdx.x, lane = tid & 63, wv = tid >> 6;
  const int bid = blockIdx.x;
  const int b = bid >> 10, h = (bid >> 5) & 31, qb = bid & 31;
  const int hk = h >> 2;
  const int l15 = lane & 15, lhi = lane >> 4;
  const int rloc = (lane >> 3) & 7, chk = lane & 7;
  const int csw = (chk ^ rloc) * 8;         // pre-swizzled source element offset
  const int sw  = (l15 & 7) << 4;           // LDS read-side XOR (bytes)
  const int qrow0 = qb*64 + wv*16;
  const f32x4 zz = {0.f, 0.f, 0.f, 0.f};

  // Q fragments (B-operand: lane row = q-local = l15)
  f16x8 qf[2];
  #pragma unroll
  for (int ks = 0; ks < 2; ++ks)
    qf[ks] = *(const f16x8*)&Qp[(size_t)(b*SEQ + qrow0 + l15)*EDIM
                                + h*DHEAD + ks*32 + lhi*8];

  const f16* Kb = Kp + (size_t)(b*SEQ)*KVD + hk*DHEAD;
  const f16* Vb = Vt + (size_t)((b*NHKV + hk)*DHEAD)*SEQ;

  // ---- pass A: denominator (scores bounded; exp2 safe in f32, no max pass) ----
  float lsum = 0.f;
  for (int kb = 0; kb < SEQ/64; ++kb) {
    #pragma unroll
    for (int i = 0; i < 2; ++i) {
      int u = wv*2 + i;
      gload_lds16(Kb + (size_t)(kb*64 + u*8 + rloc)*KVD + csw, sK + u*512);
    }
    __syncthreads();
    #pragma unroll
    for (int kt = 0; kt < 4; ++kt) {
      const char* kbase = (const char*)sK + (kt*16 + l15)*128;
      f16x8 kf0 = *(const f16x8*)(kbase + ((lhi*16) ^ sw));
      f16x8 kf1 = *(const f16x8*)(kbase + ((64 + lhi*16) ^ sw));
      f32x4 s = zz;
      s = mfma16(kf0, qf[0], s);       // swapped: row=k, col=q(l15)
      s = mfma16(kf1, qf[1], s);
      #pragma unroll
      for (int r = 0; r < 4; ++r)
        lsum += __builtin_amdgcn_exp2f(s[r] * SCALE);
    }
    __syncthreads();
  }
  float den = lsum;
  den += __shfl_xor(den, 16);
  den += __shfl_xor(den, 32);
  const float rinv = __builtin_amdgcn_rcpf(den);   // denominator for q = l15

  // ---- pass B: weights out + PV ----
  f32x4 o[4];
  #pragma unroll
  for (int dt = 0; dt < 4; ++dt) o[dt] = zz;

  f16* swv = sW + wv*1024;   // [16 q][64 k] f16
  float* wrow = wout + (size_t)((b*NHQ + h)*SEQ + qrow0)*SEQ;

  for (int kb = 0; kb < SEQ/64; ++kb) {
    #pragma unroll
    for (int i = 0; i < 2; ++i) {
      int u = wv*2 + i;
      gload_lds16(Kb + (size_t)(kb*64 + u*8 + rloc)*KVD + csw, sK + u*512);
      gload_lds16(Vb + (size_t)(u*8 + rloc)*SEQ + kb*64 + csw, sV + u*512);
    }
    __syncthreads();
    #pragma unroll
    for (int kt = 0; kt < 4; ++kt) {
      const char* kbase = (const char*)sK + (kt*16 + l15)*128;
      f16x8 kf0 = *(const f16x8*)(kbase + ((lhi*16) ^ sw));
      f16x8 kf1 = *(const f16x8*)(kbase + ((64 + lhi*16) ^ sw));
      f32x4 s = zz;
      s = mfma16(kf0, qf[0], s);
      s = mfma16(kf1, qf[1], s);
      f32x4 wvec;
      f16x4 wh;
      #pragma unroll
      for (int r = 0; r < 4; ++r) {
        float w = __builtin_amdgcn_exp2f(s[r] * SCALE) * rinv;
        wvec[r] = w;
        wh[r] = (f16)w;
      }
      // lane: q = l15, k = kb*64 + kt*16 + lhi*4 + r  -> contiguous float4
      __builtin_nontemporal_store(wvec,
          (f32x4*)(wrow + (size_t)l15*SEQ + kb*64 + kt*16 + lhi*4));
      *(f16x4*)((char*)swv + l15*128 + ((kt*32 + lhi*8) ^ sw)) = wh;
    }
    // PV: o[q][d] += w[q][k] * V^T[d][k]
    #pragma unroll
    for (int ks = 0; ks < 2; ++ks) {
      f16x8 af = *(const f16x8*)((const char*)swv + l15*128 + ((ks*64 + lhi*16) ^ sw));
      #pragma unroll
      for (int dt = 0; dt < 4; ++dt) {
        const char* vbase = (const char*)sV + (dt*16 + l15)*128;
        f16x8 vf = *(const f16x8*)(vbase + ((ks*64 + lhi*16) ^ sw));
        o[dt] = mfma16(af, vf, o[dt]);
      }
    }
    __syncthreads();
  }

  // write attn_out (f16): lane holds q = qrow0 + lhi*4 + r, d = dt*16 + l15
  #pragma unroll
  for (int dt = 0; dt < 4; ++dt)
    #pragma unroll
    for (int r = 0; r < 4; ++r)
      AO[(size_t)(b*SEQ + qrow0 + lhi*4 + r)*EDIM + h*DHEAD + dt*16 + l15]
          = (f16)o[dt][r];
}

// ---------------- launch ----------------
extern "C" void kernel_launch(void* const* d_in, const int* in_sizes, int n_in,
                              void* d_out, int out_size, void* d_ws, size_t ws_size,
                              hipStream_t stream) {
  (void)in_sizes; (void)n_in; (void)out_size; (void)ws_size;
  const float* query = (const float*)d_in[0];
  const float* key   = (const float*)d_in[1];
  const float* value = (const float*)d_in[2];
  const float* Wq    = (const float*)d_in[3];
  const float* bq    = (const float*)d_in[4];
  const float* Wk    = (const float*)d_in[5];
  const float* bk    = (const float*)d_in[6];
  const float* Wv    = (const float*)d_in[7];
  const float* bv    = (const float*)d_in[8];
  const float* Wo    = (const float*)d_in[9];
  const float* bo    = (const float*)d_in[10];

  float* out   = (float*)d_out;
  float* wattn = out + (size_t)NTOK*EDIM;

  f16* p   = (f16*)d_ws;
  f16* q16 = p;  p += (size_t)NTOK*EDIM;
  f16* k16 = p;  p += (size_t)NTOK*EDIM;
  f16* v16 = p;  p += (size_t)NTOK*EDIM;
  f16* wqT = p;  p += (size_t)EDIM*EDIM;
  f16* wkT = p;  p += (size_t)KVD*EDIM;
  f16* wvT = p;  p += (size_t)KVD*EDIM;
  f16* woT = p;  p += (size_t)EDIM*EDIM;
  f16* Qp  = p;  p += (size_t)NTOK*EDIM;
  f16* Kp  = p;  p += (size_t)NTOK*KVD;
  f16* Vp  = p;  p += (size_t)NTOK*KVD;
  f16* Vt  = p;  p += (size_t)NTOK*KVD;
  f16* AO  = p;  p += (size_t)NTOK*EDIM;

  const int n4 = NTOK*EDIM/4;
  k_cvt<<<n4/256, 256, 0, stream>>>(query, q16, n4);
  k_cvt<<<n4/256, 256, 0, stream>>>(key,   k16, n4);
  k_cvt<<<n4/256, 256, 0, stream>>>(value, v16, n4);

  k_tconv<<<dim3(EDIM/32, EDIM/32), 256, 0, stream>>>(Wq, wqT, EDIM, EDIM);
  k_tconv<<<dim3(EDIM/32, KVD/32),  256, 0, stream>>>(Wk, wkT, EDIM, KVD);
  k_tconv<<<dim3(EDIM/32, KVD/32),  256, 0, stream>>>(Wv, wvT, EDIM, KVD);
  k_tconv<<<dim3(EDIM/32, EDIM/32), 256, 0, stream>>>(Wo, woT, EDIM, EDIM);

  k_gemm<1><<<dim3(EDIM/128, NTOK/128), 256, 0, stream>>>(q16, wqT, bq, Qp, NTOK, EDIM, EDIM);
  k_gemm<1><<<dim3(KVD/128,  NTOK/128), 256, 0, stream>>>(k16, wkT, bk, Kp, NTOK, KVD,  EDIM);
  k_gemm<1><<<dim3(KVD/128,  NTOK/128), 256, 0, stream>>>(v16, wvT, bv, Vp, NTOK, KVD,  EDIM);

  k_trv<<<dim3(NB*NHKV, SEQ/64), 256, 0, stream>>>(Vp, Vt);

  k_attn<<<NB*NHQ*(SEQ/32/2), 256, 0, stream>>>(Qp, Kp, Vt, wattn, AO);

  k_gemm<0><<<dim3(EDIM/128, NTOK/128), 256, 0, stream>>>(AO, woT, bo, out, NTOK, EDIM, EDIM);
}

// Round 3
// 508.461 us; speedup vs baseline: 2.0060x; 1.1847x over previous
//
#include <hip/hip_runtime.h>
#include <stdint.h>

typedef _Float16 f16;
typedef _Float16 f16x8 __attribute__((ext_vector_type(8)));
typedef _Float16 f16x4 __attribute__((ext_vector_type(4)));
typedef float    f32x4 __attribute__((ext_vector_type(4)));

#define SEQ   2048
#define EDIM  2048
#define NHQ   32
#define NHKV  8
#define DHEAD 64
#define KVD   512
#define NB    2
#define NTOK  (NB*SEQ)
#define SCALE 0.1803368801111204f   // log2(e)/8

__device__ __forceinline__ f32x4 mfma16(f16x8 a, f16x8 b, f32x4 c) {
  return __builtin_amdgcn_mfma_f32_16x16x32_f16(a, b, c, 0, 0, 0);
}

__device__ __forceinline__ void gload_lds16(const void* g, void* l) {
  __builtin_amdgcn_global_load_lds(
      (const __attribute__((address_space(1))) void*)g,
      (__attribute__((address_space(3))) void*)l, 16, 0, 0);
}

// ---------------- fused convert f32 -> f16 for q,k,v ----------------
// dst q16,k16,v16 are contiguous in ws; i>>21 selects tensor (2^21 float4 each)
__global__ __launch_bounds__(256) void k_cvt3(const float* __restrict__ s0,
                                              const float* __restrict__ s1,
                                              const float* __restrict__ s2,
                                              f16* __restrict__ d) {
  int i = blockIdx.x * 256 + threadIdx.x;
  int t = i >> 21, j = i & ((1 << 21) - 1);
  const float* s = (t == 0) ? s0 : ((t == 1) ? s1 : s2);
  float4 v = reinterpret_cast<const float4*>(s)[j];
  f16x4 h;
  h[0] = (f16)v.x; h[1] = (f16)v.y; h[2] = (f16)v.z; h[3] = (f16)v.w;
  reinterpret_cast<f16x4*>(d)[i] = h;
}

// ---------------- transpose+convert pair: f32 [R][C] -> f16 [C][R] ----------------
__global__ __launch_bounds__(256) void k_tconv(const float* __restrict__ s0,
                                               const float* __restrict__ s1,
                                               f16* __restrict__ d0,
                                               f16* __restrict__ d1,
                                               int R, int C) {
  const float* s = blockIdx.z ? s1 : s0;
  f16* d = blockIdx.z ? d1 : d0;
  __shared__ float t[32][33];
  int tr = blockIdx.x, tc = blockIdx.y;
  int lr = threadIdx.x >> 3;
  int lc = (threadIdx.x & 7) << 2;
  float4 v = *reinterpret_cast<const float4*>(&s[(size_t)(tr*32+lr)*C + tc*32 + lc]);
  t[lr][lc+0] = v.x; t[lr][lc+1] = v.y; t[lr][lc+2] = v.z; t[lr][lc+3] = v.w;
  __syncthreads();
  f16x4 h;
  h[0] = (f16)t[lc+0][lr];
  h[1] = (f16)t[lc+1][lr];
  h[2] = (f16)t[lc+2][lr];
  h[3] = (f16)t[lc+3][lr];
  *reinterpret_cast<f16x4*>(&d[(size_t)(tc*32+lr)*R + tr*32 + lc]) = h;
}

// ---------------- transpose V: [4096][512] f16 -> Vt [16][64][2048] f16 ----------------
__global__ __launch_bounds__(256) void k_trv(const f16* __restrict__ src,
                                             f16* __restrict__ dst) {
  __shared__ f16 t[64][68];
  int bh = blockIdx.x;            // b*8 + hkv
  int st = blockIdx.y;            // s tile (64)
  int b = bh >> 3, h = bh & 7;
  #pragma unroll
  for (int i = 0; i < 4; ++i) {
    int sl = i*16 + (threadIdx.x >> 4);
    int d4 = (threadIdx.x & 15) * 4;
    *(f16x4*)&t[sl][d4] =
        *(const f16x4*)&src[(size_t)(b*SEQ + st*64 + sl)*KVD + h*DHEAD + d4];
  }
  __syncthreads();
  #pragma unroll
  for (int i = 0; i < 4; ++i) {
    int dl = i*16 + (threadIdx.x >> 4);
    int s4 = (threadIdx.x & 15) * 4;
    f16x4 v;
    v[0] = t[s4+0][dl]; v[1] = t[s4+1][dl]; v[2] = t[s4+2][dl]; v[3] = t[s4+3][dl];
    *(f16x4*)&dst[(size_t)(bh*DHEAD + dl)*SEQ + st*64 + s4] = v;
  }
}

// ---------------- GEMM: C[M,N] = A[M,K] * Bt[N,K]^T + bias ----------------
// blockIdx.z selects operand set (lets two half-size GEMMs fill the GPU in
// one launch instead of two serialized 128-block launches).
template<int F16OUT>
__global__ __launch_bounds__(256) void k_gemm(
    const f16* __restrict__ A0, const f16* __restrict__ A1,
    const f16* __restrict__ Bt0, const f16* __restrict__ Bt1,
    const float* __restrict__ bias0, const float* __restrict__ bias1,
    void* __restrict__ C0, void* __restrict__ C1,
    int M, int N, int K)
{
  const f16* A    = blockIdx.z ? A1 : A0;
  const f16* Bt   = blockIdx.z ? Bt1 : Bt0;
  const float* bias = blockIdx.z ? bias1 : bias0;
  void* Cout      = blockIdx.z ? C1 : C0;

  __shared__ f16 sA[128*64];
  __shared__ f16 sB[128*64];
  const int tid  = threadIdx.x;
  const int lane = tid & 63, wv = tid >> 6;
  const int tn = blockIdx.x, tm = blockIdx.y;
  const int wm = wv >> 1, wn = wv & 1;
  const int l15 = lane & 15, lhi = lane >> 4;

  const f32x4 zz = {0.f, 0.f, 0.f, 0.f};
  f32x4 acc[4][4];
  #pragma unroll
  for (int m = 0; m < 4; ++m)
    #pragma unroll
    for (int n = 0; n < 4; ++n) acc[m][n] = zz;

  const f16* gsrc[8];
  f16* ldst[8];
  #pragma unroll
  for (int i = 0; i < 8; ++i) {
    int u = wv*8 + i;
    int r  = (u & 15)*8 + (lane >> 3);
    int cb = ((lane & 7) << 4) ^ ((r & 7) << 4);
    if (u < 16) {
      gsrc[i] = A  + (size_t)(tm*128 + r)*K + (cb >> 1);
      ldst[i] = sA + u*512;
    } else {
      gsrc[i] = Bt + (size_t)(tn*128 + r)*K + (cb >> 1);
      ldst[i] = sB + (u - 16)*512;
    }
  }

  int aoff[2][4], boff[2][4];
  #pragma unroll
  for (int ks = 0; ks < 2; ++ks)
    #pragma unroll
    for (int m = 0; m < 4; ++m) {
      int ra = wm*64 + m*16 + l15;
      aoff[ks][m] = ra*128 + ((ks*64 + (lhi << 4)) ^ ((ra & 7) << 4));
      int rb = wn*64 + m*16 + l15;
      boff[ks][m] = rb*128 + ((ks*64 + (lhi << 4)) ^ ((rb & 7) << 4));
    }

  const int nkb = K >> 6;
  for (int kb = 0; kb < nkb; ++kb) {
    #pragma unroll
    for (int i = 0; i < 8; ++i)
      gload_lds16(gsrc[i] + kb*64, ldst[i]);
    __syncthreads();
    #pragma unroll
    for (int ks = 0; ks < 2; ++ks) {
      f16x8 af[4], bf[4];
      #pragma unroll
      for (int m = 0; m < 4; ++m)
        af[m] = *(const f16x8*)((const char*)sA + aoff[ks][m]);
      #pragma unroll
      for (int n = 0; n < 4; ++n)
        bf[n] = *(const f16x8*)((const char*)sB + boff[ks][n]);
      #pragma unroll
      for (int m = 0; m < 4; ++m)
        #pragma unroll
        for (int n = 0; n < 4; ++n)
          acc[m][n] = mfma16(af[m], bf[n], acc[m][n]);
    }
    __syncthreads();
  }

  float bcol[4];
  #pragma unroll
  for (int n = 0; n < 4; ++n)
    bcol[n] = bias[tn*128 + wn*64 + n*16 + l15];
  #pragma unroll
  for (int m = 0; m < 4; ++m)
    #pragma unroll
    for (int n = 0; n < 4; ++n)
      #pragma unroll
      for (int r = 0; r < 4; ++r) {
        int row = tm*128 + wm*64 + m*16 + lhi*4 + r;
        int col = tn*128 + wn*64 + n*16 + l15;
        float v = acc[m][n][r] + bcol[n];
        if (F16OUT) ((f16*)Cout)[(size_t)row*N + col] = (f16)v;
        else        ((float*)Cout)[(size_t)row*N + col] = v;
      }
}

// ---------------- fused GQA attention ----------------
// grid 2048, XCD-swizzled. Block = 64 q rows, 4 waves x 16 rows.
// 2-phase double-buffered K/V staging: STAGE(next) issued before compute(cur),
// one barrier per k-block -> HBM/L2 latency hides under MFMA+exp.
__global__ __launch_bounds__(256) void k_attn(
    const f16* __restrict__ Qp,   // [4096][2048]
    const f16* __restrict__ Kp,   // [4096][512]
    const f16* __restrict__ Vt,   // [16][64][2048]
    float* __restrict__ wout,     // [2][32][2048][2048]
    f16* __restrict__ AO)         // [4096][2048]
{
  __shared__ f16 sK[2][64*64];    // 2 x 8 KB
  __shared__ f16 sV[2][64*64];    // 2 x 8 KB
  __shared__ f16 sW[4][16*64];    // 8 KB, per-wave w tile
  const int tid = threadIdx.x, lane = tid & 63, wv = tid >> 6;
  // XCD swizzle: 2048 % 8 == 0 -> simple form is bijective
  const int bid = (blockIdx.x & 7) * 256 + (blockIdx.x >> 3);
  const int b = bid >> 10, h = (bid >> 5) & 31, qb = bid & 31;
  const int hk = h >> 2;
  const int l15 = lane & 15, lhi = lane >> 4;
  const int rloc = (lane >> 3) & 7, chk = lane & 7;
  const int csw = (chk ^ rloc) * 8;         // pre-swizzled source element offset
  const int sw  = (l15 & 7) << 4;           // LDS read-side XOR (bytes)
  const int qrow0 = qb*64 + wv*16;
  const f32x4 zz = {0.f, 0.f, 0.f, 0.f};

  // Q fragments (B-operand: lane row = q-local = l15)
  f16x8 qf[2];
  #pragma unroll
  for (int ks = 0; ks < 2; ++ks)
    qf[ks] = *(const f16x8*)&Qp[(size_t)(b*SEQ + qrow0 + l15)*EDIM
                                + h*DHEAD + ks*32 + lhi*8];

  const f16* Kb = Kp + (size_t)(b*SEQ)*KVD + hk*DHEAD;
  const f16* Vb = Vt + (size_t)((b*NHKV + hk)*DHEAD)*SEQ;

  // ---- pass A: denominator (scores bounded; exp2 safe in f32, no max pass) ----
  float lsum = 0.f;
  {
    // prologue
    #pragma unroll
    for (int i = 0; i < 2; ++i) {
      int u = wv*2 + i;
      gload_lds16(Kb + (size_t)(u*8 + rloc)*KVD + csw, &sK[0][u*512]);
    }
    __syncthreads();
    int buf = 0;
    for (int kb = 0; kb < SEQ/64; ++kb) {
      if (kb < SEQ/64 - 1) {
        #pragma unroll
        for (int i = 0; i < 2; ++i) {
          int u = wv*2 + i;
          gload_lds16(Kb + (size_t)((kb+1)*64 + u*8 + rloc)*KVD + csw, &sK[buf^1][u*512]);
        }
      }
      #pragma unroll
      for (int kt = 0; kt < 4; ++kt) {
        const char* kbase = (const char*)&sK[buf][0] + (kt*16 + l15)*128;
        f16x8 kf0 = *(const f16x8*)(kbase + ((lhi*16) ^ sw));
        f16x8 kf1 = *(const f16x8*)(kbase + ((64 + lhi*16) ^ sw));
        f32x4 s = zz;
        s = mfma16(kf0, qf[0], s);       // swapped: row=k, col=q(l15)
        s = mfma16(kf1, qf[1], s);
        #pragma unroll
        for (int r = 0; r < 4; ++r)
          lsum += __builtin_amdgcn_exp2f(s[r] * SCALE);
      }
      __syncthreads();
      buf ^= 1;
    }
  }
  float den = lsum;
  den += __shfl_xor(den, 16);
  den += __shfl_xor(den, 32);
  const float rinv = __builtin_amdgcn_rcpf(den);   // denominator for q = l15

  // ---- pass B: weights out + PV ----
  f32x4 o[4];
  #pragma unroll
  for (int dt = 0; dt < 4; ++dt) o[dt] = zz;

  f16* swv = &sW[wv][0];   // [16 q][64 k] f16
  float* wrow = wout + (size_t)((b*NHQ + h)*SEQ + qrow0)*SEQ;

  {
    #pragma unroll
    for (int i = 0; i < 2; ++i) {
      int u = wv*2 + i;
      gload_lds16(Kb + (size_t)(u*8 + rloc)*KVD + csw, &sK[0][u*512]);
      gload_lds16(Vb + (size_t)(u*8 + rloc)*SEQ + csw, &sV[0][u*512]);
    }
    __syncthreads();
    int buf = 0;
    for (int kb = 0; kb < SEQ/64; ++kb) {
      if (kb < SEQ/64 - 1) {
        #pragma unroll
        for (int i = 0; i < 2; ++i) {
          int u = wv*2 + i;
          gload_lds16(Kb + (size_t)((kb+1)*64 + u*8 + rloc)*KVD + csw, &sK[buf^1][u*512]);
          gload_lds16(Vb + (size_t)(u*8 + rloc)*SEQ + (kb+1)*64 + csw, &sV[buf^1][u*512]);
        }
      }
      #pragma unroll
      for (int kt = 0; kt < 4; ++kt) {
        const char* kbase = (const char*)&sK[buf][0] + (kt*16 + l15)*128;
        f16x8 kf0 = *(const f16x8*)(kbase + ((lhi*16) ^ sw));
        f16x8 kf1 = *(const f16x8*)(kbase + ((64 + lhi*16) ^ sw));
        f32x4 s = zz;
        s = mfma16(kf0, qf[0], s);
        s = mfma16(kf1, qf[1], s);
        f32x4 wvec;
        f16x4 wh;
        #pragma unroll
        for (int r = 0; r < 4; ++r) {
          float w = __builtin_amdgcn_exp2f(s[r] * SCALE) * rinv;
          wvec[r] = w;
          wh[r] = (f16)w;
        }
        // lane: q = l15, k = kb*64 + kt*16 + lhi*4 + r  -> contiguous float4
        __builtin_nontemporal_store(wvec,
            (f32x4*)(wrow + (size_t)l15*SEQ + kb*64 + kt*16 + lhi*4));
        *(f16x4*)((char*)swv + l15*128 + ((kt*32 + lhi*8) ^ sw)) = wh;
      }
      // PV: o[q][d] += w[q][k] * V^T[d][k]
      #pragma unroll
      for (int ks = 0; ks < 2; ++ks) {
        f16x8 af = *(const f16x8*)((const char*)swv + l15*128 + ((ks*64 + lhi*16) ^ sw));
        #pragma unroll
        for (int dt = 0; dt < 4; ++dt) {
          const char* vbase = (const char*)&sV[buf][0] + (dt*16 + l15)*128;
          f16x8 vf = *(const f16x8*)(vbase + ((ks*64 + lhi*16) ^ sw));
          o[dt] = mfma16(af, vf, o[dt]);
        }
      }
      __syncthreads();
      buf ^= 1;
    }
  }

  // write attn_out (f16): lane holds q = qrow0 + lhi*4 + r, d = dt*16 + l15
  #pragma unroll
  for (int dt = 0; dt < 4; ++dt)
    #pragma unroll
    for (int r = 0; r < 4; ++r)
      AO[(size_t)(b*SEQ + qrow0 + lhi*4 + r)*EDIM + h*DHEAD + dt*16 + l15]
          = (f16)o[dt][r];
}

// ---------------- launch ----------------
extern "C" void kernel_launch(void* const* d_in, const int* in_sizes, int n_in,
                              void* d_out, int out_size, void* d_ws, size_t ws_size,
                              hipStream_t stream) {
  (void)in_sizes; (void)n_in; (void)out_size; (void)ws_size;
  const float* query = (const float*)d_in[0];
  const float* key   = (const float*)d_in[1];
  const float* value = (const float*)d_in[2];
  const float* Wq    = (const float*)d_in[3];
  const float* bq    = (const float*)d_in[4];
  const float* Wk    = (const float*)d_in[5];
  const float* bk    = (const float*)d_in[6];
  const float* Wv    = (const float*)d_in[7];
  const float* bv    = (const float*)d_in[8];
  const float* Wo    = (const float*)d_in[9];
  const float* bo    = (const float*)d_in[10];

  float* out   = (float*)d_out;
  float* wattn = out + (size_t)NTOK*EDIM;

  f16* p   = (f16*)d_ws;
  f16* q16 = p;  p += (size_t)NTOK*EDIM;
  f16* k16 = p;  p += (size_t)NTOK*EDIM;
  f16* v16 = p;  p += (size_t)NTOK*EDIM;
  f16* wqT = p;  p += (size_t)EDIM*EDIM;
  f16* wkT = p;  p += (size_t)KVD*EDIM;
  f16* wvT = p;  p += (size_t)KVD*EDIM;
  f16* woT = p;  p += (size_t)EDIM*EDIM;
  f16* Qp  = p;  p += (size_t)NTOK*EDIM;
  f16* Kp  = p;  p += (size_t)NTOK*KVD;
  f16* Vp  = p;  p += (size_t)NTOK*KVD;
  f16* Vt  = p;  p += (size_t)NTOK*KVD;
  f16* AO  = p;  p += (size_t)NTOK*EDIM;

  k_cvt3<<<3*(NTOK*EDIM/4)/256, 256, 0, stream>>>(query, key, value, q16);

  k_tconv<<<dim3(EDIM/32, EDIM/32, 2), 256, 0, stream>>>(Wq, Wo, wqT, woT, EDIM, EDIM);
  k_tconv<<<dim3(EDIM/32, KVD/32, 2),  256, 0, stream>>>(Wk, Wv, wkT, wvT, EDIM, KVD);

  k_gemm<1><<<dim3(EDIM/128, NTOK/128, 1), 256, 0, stream>>>(
      q16, q16, wqT, wqT, bq, bq, Qp, Qp, NTOK, EDIM, EDIM);
  k_gemm<1><<<dim3(KVD/128, NTOK/128, 2), 256, 0, stream>>>(
      k16, v16, wkT, wvT, bk, bv, Kp, Vp, NTOK, KVD, EDIM);

  k_trv<<<dim3(NB*NHKV, SEQ/64), 256, 0, stream>>>(Vp, Vt);

  k_attn<<<NB*NHQ*(SEQ/64), 256, 0, stream>>>(Qp, Kp, Vt, wattn, AO);

  k_gemm<0><<<dim3(EDIM/128, NTOK/128, 1), 256, 0, stream>>>(
      AO, AO, woT, woT, bo, bo, out, out, NTOK, EDIM, EDIM);
}